// Round 1
// baseline (1493.205 us; speedup 1.0000x reference)
//
#include <hip/hip_runtime.h>

#define N_NODES 100000
#define N_EDGES 1600000
#define FEAT 128
#define LAYERS 4

// ---------------- CSR build (by dst) ----------------

__global__ void count_deg_kernel(const int* __restrict__ dst, int* __restrict__ deg) {
    int e = blockIdx.x * blockDim.x + threadIdx.x;
    if (e < N_EDGES) atomicAdd(&deg[dst[e]], 1);
}

// single block, 1024 threads: exclusive scan of deg -> row_ptr (N+1) and cursor copy
__global__ void build_rowptr_kernel(const int* __restrict__ deg, int* __restrict__ row_ptr,
                                    int* __restrict__ cursor) {
    __shared__ int sums[1024];
    const int t = threadIdx.x;
    const int chunk = (N_NODES + 1023) / 1024;  // 98
    const int lo = t * chunk;
    const int hi = min(lo + chunk, N_NODES);
    int s = 0;
    for (int i = lo; i < hi; ++i) s += deg[i];
    sums[t] = s;
    __syncthreads();
    // Hillis-Steele inclusive scan
    for (int off = 1; off < 1024; off <<= 1) {
        int v = (t >= off) ? sums[t - off] : 0;
        __syncthreads();
        sums[t] += v;
        __syncthreads();
    }
    int run = (t == 0) ? 0 : sums[t - 1];  // exclusive prefix
    for (int i = lo; i < hi; ++i) {
        int dv = deg[i];
        row_ptr[i] = run;
        cursor[i] = run;
        run += dv;
    }
    if (t == 1023) row_ptr[N_NODES] = sums[1023];
}

__global__ void fill_edges_kernel(const int* __restrict__ src, const int* __restrict__ dst,
                                  int* __restrict__ cursor, int* __restrict__ edge_src) {
    int e = blockIdx.x * blockDim.x + threadIdx.x;
    if (e < N_EDGES) {
        int pos = atomicAdd(&cursor[dst[e]], 1);
        edge_src[pos] = src[e];
    }
}

// ---------------- GEMM: y = relu(x @ W1 [+ p @ W2] + bias) ----------------
// x: [N,128] row-major, W: [128,128] row-major (k-major rows), y: [N,128]
// Block: 256 threads, tile = 64 nodes x 128 feats. Thread (tr=tid>>5, tc=tid&31)
// computes nodes tr*8..tr*8+7, feats tc*4..tc*4+3 (acc[8][4]).
template <bool FUSED>
__global__ __launch_bounds__(256) void gemm_relu_kernel(
    const float* __restrict__ x, const float* __restrict__ W1,
    const float* __restrict__ p, const float* __restrict__ W2,
    const float* __restrict__ bias, float* __restrict__ y) {
    __shared__ float xs[64][FEAT];
    const int n0 = blockIdx.x * 64;
    const int tid = threadIdx.x;
    const int tr = tid >> 5;   // 0..7
    const int tc = tid & 31;   // 0..31

    float acc[8][4];
#pragma unroll
    for (int r = 0; r < 8; ++r)
#pragma unroll
        for (int j = 0; j < 4; ++j) acc[r][j] = 0.f;

    const int npass = FUSED ? 2 : 1;
    for (int pass = 0; pass < npass; ++pass) {
        const float* srcm = pass ? p : x;
        const float* W = pass ? W2 : W1;
        __syncthreads();  // protect xs from previous pass readers
        const float4* s4 = (const float4*)srcm;
#pragma unroll
        for (int i = tid; i < 64 * 32; i += 256) {
            int row = i >> 5, col = i & 31;
            int n = n0 + row;
            float4 v = make_float4(0.f, 0.f, 0.f, 0.f);
            if (n < N_NODES) v = s4[(size_t)n * 32 + col];
            ((float4*)xs[row])[col] = v;
        }
        __syncthreads();
        const float4* W4 = (const float4*)W;  // [128][32] float4
        for (int k = 0; k < FEAT; k += 4) {
            float4 w0 = W4[(k + 0) * 32 + tc];
            float4 w1 = W4[(k + 1) * 32 + tc];
            float4 w2 = W4[(k + 2) * 32 + tc];
            float4 w3 = W4[(k + 3) * 32 + tc];
#pragma unroll
            for (int r = 0; r < 8; ++r) {
                float4 xv = ((const float4*)xs[tr * 8 + r])[k >> 2];
                acc[r][0] += xv.x * w0.x; acc[r][1] += xv.x * w0.y;
                acc[r][2] += xv.x * w0.z; acc[r][3] += xv.x * w0.w;
                acc[r][0] += xv.y * w1.x; acc[r][1] += xv.y * w1.y;
                acc[r][2] += xv.y * w1.z; acc[r][3] += xv.y * w1.w;
                acc[r][0] += xv.z * w2.x; acc[r][1] += xv.z * w2.y;
                acc[r][2] += xv.z * w2.z; acc[r][3] += xv.z * w2.w;
                acc[r][0] += xv.w * w3.x; acc[r][1] += xv.w * w3.y;
                acc[r][2] += xv.w * w3.z; acc[r][3] += xv.w * w3.w;
            }
        }
    }

    float4 bv = ((const float4*)bias)[tc];
#pragma unroll
    for (int r = 0; r < 8; ++r) {
        int n = n0 + tr * 8 + r;
        if (n < N_NODES) {
            float4 o;
            o.x = fmaxf(acc[r][0] + bv.x, 0.f);
            o.y = fmaxf(acc[r][1] + bv.y, 0.f);
            o.z = fmaxf(acc[r][2] + bv.z, 0.f);
            o.w = fmaxf(acc[r][3] + bv.w, 0.f);
            ((float4*)y)[(size_t)n * 32 + tc] = o;
        }
    }
}

// ---------------- segment max over CSR ----------------
// one wave per node; lane holds feats {2*lane, 2*lane+1}
__global__ __launch_bounds__(256) void seg_max_kernel(
    const float* __restrict__ h_pool, const int* __restrict__ row_ptr,
    const int* __restrict__ edge_src, float* __restrict__ pooled) {
    const int node = blockIdx.x * 4 + (threadIdx.x >> 6);
    const int lane = threadIdx.x & 63;
    if (node >= N_NODES) return;
    const int start = row_ptr[node];
    const int end = row_ptr[node + 1];
    float2 a0 = make_float2(0.f, 0.f);
    float2 a1 = make_float2(0.f, 0.f);
    int i = start;
    for (; i + 1 < end; i += 2) {
        int s0 = edge_src[i];
        int s1 = edge_src[i + 1];
        float2 v0 = *(const float2*)&h_pool[(size_t)s0 * FEAT + lane * 2];
        float2 v1 = *(const float2*)&h_pool[(size_t)s1 * FEAT + lane * 2];
        a0.x = fmaxf(a0.x, v0.x); a0.y = fmaxf(a0.y, v0.y);
        a1.x = fmaxf(a1.x, v1.x); a1.y = fmaxf(a1.y, v1.y);
    }
    if (i < end) {
        int s0 = edge_src[i];
        float2 v0 = *(const float2*)&h_pool[(size_t)s0 * FEAT + lane * 2];
        a0.x = fmaxf(a0.x, v0.x); a0.y = fmaxf(a0.y, v0.y);
    }
    float2 r;
    r.x = fmaxf(a0.x, a1.x);
    r.y = fmaxf(a0.y, a1.y);
    *(float2*)&pooled[(size_t)node * FEAT + lane * 2] = r;
}

// ---------------- launch ----------------

extern "C" void kernel_launch(void* const* d_in, const int* in_sizes, int n_in,
                              void* d_out, int out_size, void* d_ws, size_t ws_size,
                              hipStream_t stream) {
    const float* feats = (const float*)d_in[0];
    const float* Wp = (const float*)d_in[1];
    const float* bp = (const float*)d_in[2];
    const float* Ws = (const float*)d_in[3];
    const float* Wn = (const float*)d_in[4];
    const float* bb = (const float*)d_in[5];
    const int* src = (const int*)d_in[6];
    const int* dst = (const int*)d_in[7];
    float* out = (float*)d_out;

    const size_t NF = (size_t)N_NODES * FEAT;
    char* ws = (char*)d_ws;
    float* bufH = (float*)ws; ws += NF * sizeof(float);
    float* bufP = (float*)ws; ws += NF * sizeof(float);
    float* bufA = (float*)ws; ws += NF * sizeof(float);
    int* deg = (int*)ws;      ws += (size_t)N_NODES * sizeof(int);
    int* row_ptr = (int*)ws;  ws += (size_t)(N_NODES + 1) * sizeof(int);
    int* cursor = (int*)ws;   ws += (size_t)N_NODES * sizeof(int);
    int* edge_src = (int*)ws;

    // CSR build (graph static across layers)
    hipMemsetAsync(deg, 0, (size_t)N_NODES * sizeof(int), stream);
    count_deg_kernel<<<(N_EDGES + 255) / 256, 256, 0, stream>>>(dst, deg);
    build_rowptr_kernel<<<1, 1024, 0, stream>>>(deg, row_ptr, cursor);
    fill_edges_kernel<<<(N_EDGES + 255) / 256, 256, 0, stream>>>(src, dst, cursor, edge_src);

    const int gemm_grid = (N_NODES + 63) / 64;  // 1563
    const int seg_grid = (N_NODES + 3) / 4;     // 25000

    // x chain: feats -> bufA -> out -> bufA -> out
    const float* x_in[LAYERS] = {feats, bufA, out, bufA};
    float* x_out[LAYERS] = {bufA, out, bufA, out};

    for (int l = 0; l < LAYERS; ++l) {
        const float* Wpl = Wp + (size_t)l * FEAT * FEAT;
        const float* bpl = bp + (size_t)l * FEAT;
        const float* Wsl = Ws + (size_t)l * FEAT * FEAT;
        const float* Wnl = Wn + (size_t)l * FEAT * FEAT;
        const float* bl = bb + (size_t)l * FEAT;

        gemm_relu_kernel<false><<<gemm_grid, 256, 0, stream>>>(
            x_in[l], Wpl, nullptr, nullptr, bpl, bufH);
        seg_max_kernel<<<seg_grid, 256, 0, stream>>>(bufH, row_ptr, edge_src, bufP);
        gemm_relu_kernel<true><<<gemm_grid, 256, 0, stream>>>(
            x_in[l], Wsl, bufP, Wnl, bl, x_out[l]);
    }
}

// Round 3
// 1309.851 us; speedup vs baseline: 1.1400x; 1.1400x over previous
//
#include <hip/hip_runtime.h>

#define N_NODES 100000
#define N_EDGES 1600000
#define FEAT 128
#define LAYERS 4
#define SCAN_BLK 256
#define N_SCAN_BLKS ((N_NODES + SCAN_BLK - 1) / SCAN_BLK)  // 391

// ---------------- CSR build (by dst) ----------------

__global__ void count_deg_kernel(const int* __restrict__ dst, int* __restrict__ deg) {
    int e = blockIdx.x * blockDim.x + threadIdx.x;
    if (e < N_EDGES) atomicAdd(&deg[dst[e]], 1);
}

// phase A: per-block sums of deg
__global__ __launch_bounds__(SCAN_BLK) void blk_sum_kernel(const int* __restrict__ deg,
                                                           int* __restrict__ blk_sums) {
    int i = blockIdx.x * SCAN_BLK + threadIdx.x;
    int v = (i < N_NODES) ? deg[i] : 0;
#pragma unroll
    for (int off = 32; off; off >>= 1) v += __shfl_down(v, off, 64);
    __shared__ int ws_[SCAN_BLK / 64];
    if ((threadIdx.x & 63) == 0) ws_[threadIdx.x >> 6] = v;
    __syncthreads();
    if (threadIdx.x == 0) {
        int s = 0;
#pragma unroll
        for (int w = 0; w < SCAN_BLK / 64; ++w) s += ws_[w];
        blk_sums[blockIdx.x] = s;
    }
}

// phase B: single block scans the 391 block sums -> exclusive offsets (in place)
__global__ __launch_bounds__(512) void scan_blk_kernel(int* __restrict__ blk_sums) {
    __shared__ int s[512];
    const int t = threadIdx.x;
    s[t] = (t < N_SCAN_BLKS) ? blk_sums[t] : 0;
    __syncthreads();
    for (int off = 1; off < 512; off <<= 1) {
        int v = (t >= off) ? s[t - off] : 0;
        __syncthreads();
        s[t] += v;
        __syncthreads();
    }
    if (t < N_SCAN_BLKS) blk_sums[t] = (t == 0) ? 0 : s[t - 1];
}

// phase C: per-block exclusive rescan + offset -> row_ptr, cursor
__global__ __launch_bounds__(SCAN_BLK) void write_rowptr_kernel(
    const int* __restrict__ deg, const int* __restrict__ blk_off,
    int* __restrict__ row_ptr, int* __restrict__ cursor) {
    __shared__ int s[SCAN_BLK];
    const int t = threadIdx.x;
    const int i = blockIdx.x * SCAN_BLK + t;
    int v = (i < N_NODES) ? deg[i] : 0;
    s[t] = v;
    __syncthreads();
    for (int off = 1; off < SCAN_BLK; off <<= 1) {
        int u = (t >= off) ? s[t - off] : 0;
        __syncthreads();
        s[t] += u;
        __syncthreads();
    }
    int excl = s[t] - v + blk_off[blockIdx.x];
    if (i < N_NODES) {
        row_ptr[i] = excl;
        cursor[i] = excl;
    }
    if (i == 0) row_ptr[N_NODES] = N_EDGES;
}

__global__ void fill_edges_kernel(const int* __restrict__ src, const int* __restrict__ dst,
                                  int* __restrict__ cursor, int* __restrict__ edge_src) {
    int e = blockIdx.x * blockDim.x + threadIdx.x;
    if (e < N_EDGES) {
        int pos = atomicAdd(&cursor[dst[e]], 1);
        edge_src[pos] = src[e];
    }
}

// ---------------- GEMM: y = relu(x @ W1 [+ p @ W2] + bias) ----------------
// NOTE: y may alias the (dead) h_pool buffer but must NOT alias x or p.
template <bool FUSED>
__global__ __launch_bounds__(256) void gemm_relu_kernel(
    const float* __restrict__ x, const float* __restrict__ W1,
    const float* __restrict__ p, const float* __restrict__ W2,
    const float* __restrict__ bias, float* __restrict__ y) {
    __shared__ float xs[64][FEAT];
    const int n0 = blockIdx.x * 64;
    const int tid = threadIdx.x;
    const int tr = tid >> 5;   // 0..7
    const int tc = tid & 31;   // 0..31

    float acc[8][4];
#pragma unroll
    for (int r = 0; r < 8; ++r)
#pragma unroll
        for (int j = 0; j < 4; ++j) acc[r][j] = 0.f;

    const int npass = FUSED ? 2 : 1;
    for (int pass = 0; pass < npass; ++pass) {
        const float* srcm = pass ? p : x;
        const float* W = pass ? W2 : W1;
        __syncthreads();
        const float4* s4 = (const float4*)srcm;
#pragma unroll
        for (int i = tid; i < 64 * 32; i += 256) {
            int row = i >> 5, col = i & 31;
            int n = n0 + row;
            float4 v = make_float4(0.f, 0.f, 0.f, 0.f);
            if (n < N_NODES) v = s4[(size_t)n * 32 + col];
            ((float4*)xs[row])[col] = v;
        }
        __syncthreads();
        const float4* W4 = (const float4*)W;
        for (int k = 0; k < FEAT; k += 4) {
            float4 w0 = W4[(k + 0) * 32 + tc];
            float4 w1 = W4[(k + 1) * 32 + tc];
            float4 w2 = W4[(k + 2) * 32 + tc];
            float4 w3 = W4[(k + 3) * 32 + tc];
#pragma unroll
            for (int r = 0; r < 8; ++r) {
                float4 xv = ((const float4*)xs[tr * 8 + r])[k >> 2];
                acc[r][0] += xv.x * w0.x; acc[r][1] += xv.x * w0.y;
                acc[r][2] += xv.x * w0.z; acc[r][3] += xv.x * w0.w;
                acc[r][0] += xv.y * w1.x; acc[r][1] += xv.y * w1.y;
                acc[r][2] += xv.y * w1.z; acc[r][3] += xv.y * w1.w;
                acc[r][0] += xv.z * w2.x; acc[r][1] += xv.z * w2.y;
                acc[r][2] += xv.z * w2.z; acc[r][3] += xv.z * w2.w;
                acc[r][0] += xv.w * w3.x; acc[r][1] += xv.w * w3.y;
                acc[r][2] += xv.w * w3.z; acc[r][3] += xv.w * w3.w;
            }
        }
    }

    float4 bv = ((const float4*)bias)[tc];
#pragma unroll
    for (int r = 0; r < 8; ++r) {
        int n = n0 + tr * 8 + r;
        if (n < N_NODES) {
            float4 o;
            o.x = fmaxf(acc[r][0] + bv.x, 0.f);
            o.y = fmaxf(acc[r][1] + bv.y, 0.f);
            o.z = fmaxf(acc[r][2] + bv.z, 0.f);
            o.w = fmaxf(acc[r][3] + bv.w, 0.f);
            ((float4*)y)[(size_t)n * 32 + tc] = o;
        }
    }
}

// ---------------- segment max over CSR ----------------
__global__ __launch_bounds__(256) void seg_max_kernel(
    const float* __restrict__ h_pool, const int* __restrict__ row_ptr,
    const int* __restrict__ edge_src, float* __restrict__ pooled) {
    const int node = blockIdx.x * 4 + (threadIdx.x >> 6);
    const int lane = threadIdx.x & 63;
    if (node >= N_NODES) return;
    const int start = row_ptr[node];
    const int end = row_ptr[node + 1];
    float2 a0 = make_float2(0.f, 0.f);
    float2 a1 = make_float2(0.f, 0.f);
    int i = start;
    for (; i + 1 < end; i += 2) {
        int s0 = edge_src[i];
        int s1 = edge_src[i + 1];
        float2 v0 = *(const float2*)&h_pool[(size_t)s0 * FEAT + lane * 2];
        float2 v1 = *(const float2*)&h_pool[(size_t)s1 * FEAT + lane * 2];
        a0.x = fmaxf(a0.x, v0.x); a0.y = fmaxf(a0.y, v0.y);
        a1.x = fmaxf(a1.x, v1.x); a1.y = fmaxf(a1.y, v1.y);
    }
    if (i < end) {
        int s0 = edge_src[i];
        float2 v0 = *(const float2*)&h_pool[(size_t)s0 * FEAT + lane * 2];
        a0.x = fmaxf(a0.x, v0.x); a0.y = fmaxf(a0.y, v0.y);
    }
    float2 r;
    r.x = fmaxf(a0.x, a1.x);
    r.y = fmaxf(a0.y, a1.y);
    *(float2*)&pooled[(size_t)node * FEAT + lane * 2] = r;
}

// ---------------- launch ----------------
// Workspace layout (static sizes first; total ~110 MB, far below the
// R1-proven 161 MB bound):
//   edge_src: 6.4 MB | deg/row_ptr/cursor: 1.2 MB | blk_sums 2 KB |
//   bufP: 51.2 MB | bufA: 51.2 MB
// Buffer chain per layer (h_pool buffer is dead after seg_max, so x' reuses it):
//   L0: x=feats h=bufA p=bufP x'=bufA
//   L1: x=bufA  h=out  p=bufP x'=out
//   L2: x=out   h=bufA p=bufP x'=bufA
//   L3: x=bufA  h=out  p=bufP x'=out   (final lands in d_out)

extern "C" void kernel_launch(void* const* d_in, const int* in_sizes, int n_in,
                              void* d_out, int out_size, void* d_ws, size_t ws_size,
                              hipStream_t stream) {
    const float* feats = (const float*)d_in[0];
    const float* Wp = (const float*)d_in[1];
    const float* bp = (const float*)d_in[2];
    const float* Ws = (const float*)d_in[3];
    const float* Wn = (const float*)d_in[4];
    const float* bb = (const float*)d_in[5];
    const int* src = (const int*)d_in[6];
    const int* dst = (const int*)d_in[7];
    float* out = (float*)d_out;

    const size_t NF = (size_t)N_NODES * FEAT;
    char* ws = (char*)d_ws;
    int* edge_src = (int*)ws; ws += (size_t)N_EDGES * sizeof(int);
    int* deg = (int*)ws;      ws += (size_t)N_NODES * sizeof(int);
    int* row_ptr = (int*)ws;  ws += (size_t)(N_NODES + 1) * sizeof(int);
    int* cursor = (int*)ws;   ws += (size_t)N_NODES * sizeof(int);
    int* blk_sums = (int*)ws; ws += (size_t)512 * sizeof(int);
    float* bufP = (float*)ws; ws += NF * sizeof(float);
    float* bufA = (float*)ws;

    // CSR build (graph static across layers)
    hipMemsetAsync(deg, 0, (size_t)N_NODES * sizeof(int), stream);
    count_deg_kernel<<<(N_EDGES + 255) / 256, 256, 0, stream>>>(dst, deg);
    blk_sum_kernel<<<N_SCAN_BLKS, SCAN_BLK, 0, stream>>>(deg, blk_sums);
    scan_blk_kernel<<<1, 512, 0, stream>>>(blk_sums);
    write_rowptr_kernel<<<N_SCAN_BLKS, SCAN_BLK, 0, stream>>>(deg, blk_sums, row_ptr, cursor);
    fill_edges_kernel<<<(N_EDGES + 255) / 256, 256, 0, stream>>>(src, dst, cursor, edge_src);

    const int gemm_grid = (N_NODES + 63) / 64;  // 1563
    const int seg_grid = (N_NODES + 3) / 4;     // 25000

    const float* x_in[LAYERS] = {feats, bufA, out, bufA};
    float* hx[LAYERS] = {bufA, out, bufA, out};  // h_pool target == x' target

    for (int l = 0; l < LAYERS; ++l) {
        const float* Wpl = Wp + (size_t)l * FEAT * FEAT;
        const float* bpl = bp + (size_t)l * FEAT;
        const float* Wsl = Ws + (size_t)l * FEAT * FEAT;
        const float* Wnl = Wn + (size_t)l * FEAT * FEAT;
        const float* bl = bb + (size_t)l * FEAT;

        gemm_relu_kernel<false><<<gemm_grid, 256, 0, stream>>>(
            x_in[l], Wpl, nullptr, nullptr, bpl, hx[l]);
        seg_max_kernel<<<seg_grid, 256, 0, stream>>>(hx[l], row_ptr, edge_src, bufP);
        gemm_relu_kernel<true><<<gemm_grid, 256, 0, stream>>>(
            x_in[l], Wsl, bufP, Wnl, bl, hx[l]);
    }
}

// Round 4
// 1071.410 us; speedup vs baseline: 1.3937x; 1.2225x over previous
//
#include <hip/hip_runtime.h>

#define N_NODES 100000
#define N_EDGES 1600000
#define FEAT 128
#define LAYERS 4
#define SCAN_BLK 256
#define N_SCAN_BLKS ((N_NODES + SCAN_BLK - 1) / SCAN_BLK)  // 391

typedef __attribute__((ext_vector_type(8))) short bf16x8;   // 8 bf16 in 4 VGPRs
typedef __attribute__((ext_vector_type(4))) float f32x4;

__device__ __forceinline__ unsigned short f2b(float f) {   // f32 -> bf16 RNE
    union { float f; unsigned int u; } v; v.f = f;
    unsigned int u = v.u;
    return (unsigned short)((u + 0x7fffu + ((u >> 16) & 1u)) >> 16);
}

// ---------------- CSR build (by dst) ----------------

__global__ void count_deg_kernel(const int* __restrict__ dst, int* __restrict__ deg) {
    int e = blockIdx.x * blockDim.x + threadIdx.x;
    if (e < N_EDGES) atomicAdd(&deg[dst[e]], 1);
}

__global__ __launch_bounds__(SCAN_BLK) void blk_sum_kernel(const int* __restrict__ deg,
                                                           int* __restrict__ blk_sums) {
    int i = blockIdx.x * SCAN_BLK + threadIdx.x;
    int v = (i < N_NODES) ? deg[i] : 0;
#pragma unroll
    for (int off = 32; off; off >>= 1) v += __shfl_down(v, off, 64);
    __shared__ int ws_[SCAN_BLK / 64];
    if ((threadIdx.x & 63) == 0) ws_[threadIdx.x >> 6] = v;
    __syncthreads();
    if (threadIdx.x == 0) {
        int s = 0;
#pragma unroll
        for (int w = 0; w < SCAN_BLK / 64; ++w) s += ws_[w];
        blk_sums[blockIdx.x] = s;
    }
}

__global__ __launch_bounds__(512) void scan_blk_kernel(int* __restrict__ blk_sums) {
    __shared__ int s[512];
    const int t = threadIdx.x;
    s[t] = (t < N_SCAN_BLKS) ? blk_sums[t] : 0;
    __syncthreads();
    for (int off = 1; off < 512; off <<= 1) {
        int v = (t >= off) ? s[t - off] : 0;
        __syncthreads();
        s[t] += v;
        __syncthreads();
    }
    if (t < N_SCAN_BLKS) blk_sums[t] = (t == 0) ? 0 : s[t - 1];
}

__global__ __launch_bounds__(SCAN_BLK) void write_rowptr_kernel(
    const int* __restrict__ deg, const int* __restrict__ blk_off,
    int* __restrict__ row_ptr, int* __restrict__ cursor) {
    __shared__ int s[SCAN_BLK];
    const int t = threadIdx.x;
    const int i = blockIdx.x * SCAN_BLK + t;
    int v = (i < N_NODES) ? deg[i] : 0;
    s[t] = v;
    __syncthreads();
    for (int off = 1; off < SCAN_BLK; off <<= 1) {
        int u = (t >= off) ? s[t - off] : 0;
        __syncthreads();
        s[t] += u;
        __syncthreads();
    }
    int excl = s[t] - v + blk_off[blockIdx.x];
    if (i < N_NODES) {
        row_ptr[i] = excl;
        cursor[i] = excl;
    }
    if (i == 0) row_ptr[N_NODES] = N_EDGES;
}

__global__ void fill_edges_kernel(const int* __restrict__ src, const int* __restrict__ dst,
                                  int* __restrict__ cursor, int* __restrict__ edge_src) {
    int e = blockIdx.x * blockDim.x + threadIdx.x;
    if (e < N_EDGES) {
        int pos = atomicAdd(&cursor[dst[e]], 1);
        edge_src[pos] = src[e];
    }
}

// ---------------- weight convert: Wt[m][n][k] = bf16(W[m][k][n]) ----------------
// 12 matrices (Wp0-3, Ws0-3, Wn0-3), 64x64 LDS-tiled transpose, coalesced both ways
__global__ __launch_bounds__(256) void convert_wt_kernel(
    const float* __restrict__ Wp, const float* __restrict__ Ws,
    const float* __restrict__ Wn, unsigned short* __restrict__ wt) {
    __shared__ float tile[64][65];
    const int m = blockIdx.x >> 2;
    const int tij = blockIdx.x & 3;
    const int ti = tij >> 1, tj = tij & 1;
    const float* W = (m < 4) ? Wp + (size_t)m * 16384
                   : (m < 8) ? Ws + (size_t)(m - 4) * 16384
                             : Wn + (size_t)(m - 8) * 16384;
#pragma unroll
    for (int i = 0; i < 16; ++i) {
        int e = i * 256 + threadIdx.x;
        int r = e >> 6, c = e & 63;
        tile[r][c] = W[(size_t)(ti * 64 + r) * 128 + tj * 64 + c];
    }
    __syncthreads();
#pragma unroll
    for (int i = 0; i < 16; ++i) {
        int e = i * 256 + threadIdx.x;
        int r = e >> 6, c = e & 63;
        wt[(size_t)m * 16384 + (size_t)(tj * 64 + r) * 128 + ti * 64 + c] = f2b(tile[c][r]);
    }
}

// ---------------- MFMA GEMM ----------------
// y = relu(x @ W1 [+ p @ W2] + bias)
// x: [N,128] f32; p: [N,128] bf16; W*t: [128][128] bf16 TRANSPOSED (n-major, k inner)
// FUSED=false -> write bf16 yh; FUSED=true -> write f32 yf.
// Block 256 thr = 4 waves; tile 64 rows x 128 cols; wave w owns rows [16w,16w+16).
// mfma_f32_16x16x32_bf16: A row=lane&15, k=8*(lane>>4)+j; B col=lane&15, same k;
// C/D col=lane&15, row=4*(lane>>4)+reg.
template <bool FUSED>
__global__ __launch_bounds__(256) void gemm_mfma_kernel(
    const float* __restrict__ x, const unsigned short* __restrict__ p,
    const unsigned short* __restrict__ W1t, const unsigned short* __restrict__ W2t,
    const float* __restrict__ bias, float* __restrict__ yf,
    unsigned short* __restrict__ yh) {
    __shared__ unsigned short xs[64 * FEAT];  // 16 KB, XOR-swizzled
    const int tid = threadIdx.x;
    const int wv = tid >> 6;
    const int lane = tid & 63;
    const int l15 = lane & 15;
    const int lhi = lane >> 4;
    const int n0 = blockIdx.x * 64;

    f32x4 acc[8];
#pragma unroll
    for (int t = 0; t < 8; ++t) acc[t] = (f32x4)(0.f);

    const int npass = FUSED ? 2 : 1;
    for (int pass = 0; pass < npass; ++pass) {
        __syncthreads();  // protect xs from prior readers
        if (pass == 0) {
#pragma unroll
            for (int i = 0; i < 4; ++i) {
                int chunk = i * 256 + tid;      // 0..1023
                int row = chunk >> 4;           // 0..63
                int c8 = chunk & 15;            // 8-col group
                int n = n0 + row;
                float4 v0 = make_float4(0.f, 0.f, 0.f, 0.f), v1 = v0;
                if (n < N_NODES) {
                    const float4* g = (const float4*)(x + (size_t)n * FEAT + c8 * 8);
                    v0 = g[0]; v1 = g[1];
                }
                unsigned short h[8];
                h[0] = f2b(v0.x); h[1] = f2b(v0.y); h[2] = f2b(v0.z); h[3] = f2b(v0.w);
                h[4] = f2b(v1.x); h[5] = f2b(v1.y); h[6] = f2b(v1.z); h[7] = f2b(v1.w);
                int byte = (row * 256 + c8 * 16) ^ ((row & 7) << 4);
                *(bf16x8*)((char*)xs + byte) = *(bf16x8*)h;
            }
        } else {
#pragma unroll
            for (int i = 0; i < 4; ++i) {
                int chunk = i * 256 + tid;
                int row = chunk >> 4;
                int c8 = chunk & 15;
                int n = n0 + row;
                float4 v = make_float4(0.f, 0.f, 0.f, 0.f);
                if (n < N_NODES) v = *(const float4*)(p + (size_t)n * FEAT + c8 * 8);
                int byte = (row * 256 + c8 * 16) ^ ((row & 7) << 4);
                *(float4*)((char*)xs + byte) = v;
            }
        }
        __syncthreads();

        const unsigned short* Wt = pass ? W2t : W1t;
        const int arow = 16 * wv + l15;
        bf16x8 afrag[4];
#pragma unroll
        for (int kk = 0; kk < 4; ++kk) {
            int byte = (arow * 256 + (kk * 32 + lhi * 8) * 2) ^ ((arow & 7) << 4);
            afrag[kk] = *(const bf16x8*)((const char*)xs + byte);
        }
#pragma unroll
        for (int nt = 0; nt < 8; ++nt) {
            const int ncol = nt * 16 + l15;
#pragma unroll
            for (int kk = 0; kk < 4; ++kk) {
                bf16x8 bfrag = *(const bf16x8*)(Wt + (size_t)ncol * FEAT + kk * 32 + lhi * 8);
                acc[nt] = __builtin_amdgcn_mfma_f32_16x16x32_bf16(afrag[kk], bfrag, acc[nt], 0, 0, 0);
            }
        }
    }

    // epilogue: row = n0 + 16*wv + 4*lhi + r, col = nt*16 + l15
    const int rbase = n0 + 16 * wv + 4 * lhi;
#pragma unroll
    for (int nt = 0; nt < 8; ++nt) {
        const int col = nt * 16 + l15;
        const float bv = bias[col];
#pragma unroll
        for (int r = 0; r < 4; ++r) {
            int n = rbase + r;
            if (n < N_NODES) {
                float v = fmaxf(acc[nt][r] + bv, 0.f);
                if (FUSED) yf[(size_t)n * FEAT + col] = v;
                else       yh[(size_t)n * FEAT + col] = f2b(v);
            }
        }
    }
}

// ---------------- segment max over CSR (bf16 rows) ----------------
// one wave per node; lane holds feats {2*lane, 2*lane+1} (4B/lane, 256B/row)
__global__ __launch_bounds__(256) void seg_max_kernel(
    const unsigned short* __restrict__ h_pool, const int* __restrict__ row_ptr,
    const int* __restrict__ edge_src, unsigned short* __restrict__ pooled) {
    const int node = blockIdx.x * 4 + (threadIdx.x >> 6);
    const int lane = threadIdx.x & 63;
    if (node >= N_NODES) return;
    const int start = row_ptr[node];
    const int end = row_ptr[node + 1];
    float a0x = 0.f, a0y = 0.f, a1x = 0.f, a1y = 0.f;
    int i = start;
    for (; i + 1 < end; i += 2) {
        unsigned int v0 = *(const unsigned int*)(h_pool + (size_t)edge_src[i] * FEAT + lane * 2);
        unsigned int v1 = *(const unsigned int*)(h_pool + (size_t)edge_src[i + 1] * FEAT + lane * 2);
        a0x = fmaxf(a0x, __uint_as_float(v0 << 16));
        a0y = fmaxf(a0y, __uint_as_float(v0 & 0xffff0000u));
        a1x = fmaxf(a1x, __uint_as_float(v1 << 16));
        a1y = fmaxf(a1y, __uint_as_float(v1 & 0xffff0000u));
    }
    if (i < end) {
        unsigned int v0 = *(const unsigned int*)(h_pool + (size_t)edge_src[i] * FEAT + lane * 2);
        a0x = fmaxf(a0x, __uint_as_float(v0 << 16));
        a0y = fmaxf(a0y, __uint_as_float(v0 & 0xffff0000u));
    }
    float rx = fmaxf(a0x, a1x);
    float ry = fmaxf(a0y, a1y);
    // rx/ry are exact bf16 values (h_pool>=0, init 0) -> truncation is exact
    unsigned int o = (__float_as_uint(rx) >> 16) | (__float_as_uint(ry) & 0xffff0000u);
    *(unsigned int*)(pooled + (size_t)node * FEAT + lane * 2) = o;
}

// ---------------- launch ----------------
// ws layout (~110 MB, well under the R1-proven 161 MB):
//   edge_src 6.4MB | deg 0.4 | row_ptr 0.4 | cursor 0.4 | blk 2KB |
//   wt (12x128x128 bf16) 0.39MB | bufH bf16 25.6 | bufP bf16 25.6 | bufA f32 51.2
// x chain f32: feats -> bufA -> out -> bufA -> out

extern "C" void kernel_launch(void* const* d_in, const int* in_sizes, int n_in,
                              void* d_out, int out_size, void* d_ws, size_t ws_size,
                              hipStream_t stream) {
    const float* feats = (const float*)d_in[0];
    const float* Wp = (const float*)d_in[1];
    const float* bp = (const float*)d_in[2];
    const float* Ws = (const float*)d_in[3];
    const float* Wn = (const float*)d_in[4];
    const float* bb = (const float*)d_in[5];
    const int* src = (const int*)d_in[6];
    const int* dst = (const int*)d_in[7];
    float* out = (float*)d_out;

    const size_t NF = (size_t)N_NODES * FEAT;
    char* ws = (char*)d_ws;
    int* edge_src = (int*)ws;        ws += (size_t)N_EDGES * sizeof(int);
    int* deg = (int*)ws;             ws += (size_t)N_NODES * sizeof(int);
    int* row_ptr = (int*)ws;         ws += (size_t)(N_NODES + 4) * sizeof(int);
    int* cursor = (int*)ws;          ws += (size_t)N_NODES * sizeof(int);
    int* blk_sums = (int*)ws;        ws += (size_t)512 * sizeof(int);
    unsigned short* wt = (unsigned short*)ws; ws += (size_t)12 * 128 * 128 * sizeof(unsigned short);
    unsigned short* bufH = (unsigned short*)ws; ws += NF * sizeof(unsigned short);
    unsigned short* bufP = (unsigned short*)ws; ws += NF * sizeof(unsigned short);
    float* bufA = (float*)ws;

    // CSR build + weight convert (graph/weights static across layers)
    hipMemsetAsync(deg, 0, (size_t)N_NODES * sizeof(int), stream);
    count_deg_kernel<<<(N_EDGES + 255) / 256, 256, 0, stream>>>(dst, deg);
    blk_sum_kernel<<<N_SCAN_BLKS, SCAN_BLK, 0, stream>>>(deg, blk_sums);
    scan_blk_kernel<<<1, 512, 0, stream>>>(blk_sums);
    write_rowptr_kernel<<<N_SCAN_BLKS, SCAN_BLK, 0, stream>>>(deg, blk_sums, row_ptr, cursor);
    fill_edges_kernel<<<(N_EDGES + 255) / 256, 256, 0, stream>>>(src, dst, cursor, edge_src);
    convert_wt_kernel<<<48, 256, 0, stream>>>(Wp, Ws, Wn, wt);

    const int gemm_grid = (N_NODES + 63) / 64;  // 1563
    const int seg_grid = (N_NODES + 3) / 4;     // 25000

    const float* x_in[LAYERS] = {feats, bufA, out, bufA};
    float* x_out[LAYERS] = {bufA, out, bufA, out};

    for (int l = 0; l < LAYERS; ++l) {
        const unsigned short* WpT = wt + (size_t)l * 16384;
        const unsigned short* WsT = wt + (size_t)(4 + l) * 16384;
        const unsigned short* WnT = wt + (size_t)(8 + l) * 16384;
        const float* bpl = bp + (size_t)l * FEAT;
        const float* bl = bb + (size_t)l * FEAT;

        gemm_mfma_kernel<false><<<gemm_grid, 256, 0, stream>>>(
            x_in[l], nullptr, WpT, nullptr, bpl, nullptr, bufH);
        seg_max_kernel<<<seg_grid, 256, 0, stream>>>(bufH, row_ptr, edge_src, bufP);
        gemm_mfma_kernel<true><<<gemm_grid, 256, 0, stream>>>(
            x_in[l], bufP, WsT, WnT, bl, x_out[l], nullptr);
    }
}